// Round 11
// baseline (143.568 us; speedup 1.0000x reference)
//
#include <hip/hip_runtime.h>
#include <math.h>

#define T_ 128
#define NPROJ 2176  // cols: [0,512)=Q [512,1024)=K [1024,1536)=V [1536,1600)=beta [1600,1664)=tg [1664,2176)=gate
#define CH 32       // scan chunk

typedef __attribute__((ext_vector_type(8))) short short8;
typedef __attribute__((ext_vector_type(4))) float float4v;
typedef __attribute__((ext_vector_type(2))) float float2v;

__device__ __forceinline__ ushort f2bf(float x) {
    unsigned u = __float_as_uint(x);
    u += 0x7FFF + ((u >> 16) & 1);   // RNE
    return (ushort)(u >> 16);
}
__device__ __forceinline__ unsigned pack_bf(float a, float b) {
    unsigned ua = (__float_as_uint(a) + 0x8000u) >> 16;
    unsigned ub = (__float_as_uint(b) + 0x8000u) & 0xffff0000u;
    return ua | ub;
}
__device__ __forceinline__ float bf_lo(unsigned w) { return __uint_as_float(w << 16); }
__device__ __forceinline__ float bf_hi(unsigned w) { return __uint_as_float(w & 0xffff0000u); }

template<int CTRL>
__device__ __forceinline__ float dpp_add(float x) {
    int xi = __float_as_int(x);
    int yi = __builtin_amdgcn_update_dpp(xi, xi, CTRL, 0xF, 0xF, false);
    return x + __int_as_float(yi);
}

// ---------------- Kernel 1: prep (unchanged from R10) ----------------------------------
__global__ __launch_bounds__(256) void prep_kernel(
    const float* __restrict__ x,
    const float* __restrict__ Wq, const float* __restrict__ Wk,
    const float* __restrict__ Wv, const float* __restrict__ Wb,
    const float* __restrict__ Wtg, const float* __restrict__ Wg,
    const float* __restrict__ Wo,
    const float* __restrict__ mode_logits, const float* __restrict__ log_decay,
    const float* __restrict__ ols,
    float* __restrict__ cosw, float* __restrict__ sinw,
    float* __restrict__ rho, float* __restrict__ modew,
    ushort* __restrict__ xb, ushort* __restrict__ wtb, ushort* __restrict__ wotb,
    float* __restrict__ Acomb)
{
    __shared__ ushort tile[64][68];
    const int blk = blockIdx.x, tid = threadIdx.x;
    if (blk < 16) {
        int idx = blk * 256 + tid;
        if (idx >= 64 * 64) return;
        int t = idx >> 6;
        int k = idx & 63;
        int h = t >> 3;
        if (k == 0) {
            float ld = log_decay[t];
            rho[t] = 1.0f / (1.0f + expf(ld));
            float m = -1e30f;
            for (int i = 0; i < 8; i++) m = fmaxf(m, mode_logits[h * 8 + i]);
            float sum = 0.0f;
            for (int i = 0; i < 8; i++) sum += expf(mode_logits[h * 8 + i] - m);
            modew[t] = expf(mode_logits[t] - m) / sum;
        }
        float osc = expf(ols[t]);
        int p = k >> 1;
        float invf = expf(-((float)(2 * p) / 64.0f) * logf(10000.0f));
        float w = osc * invf;
        cosw[idx] = cosf(w);
        sinw[idx] = sinf(w);
        return;
    }
    if (blk < 80) {
        int base = (blk - 16) * 4096 + tid * 16;
        float4 f0 = *(const float4*)&x[base];
        float4 f1 = *(const float4*)&x[base + 4];
        float4 f2 = *(const float4*)&x[base + 8];
        float4 f3 = *(const float4*)&x[base + 12];
        short8 o0, o1;
        o0[0]=f2bf(f0.x); o0[1]=f2bf(f0.y); o0[2]=f2bf(f0.z); o0[3]=f2bf(f0.w);
        o0[4]=f2bf(f1.x); o0[5]=f2bf(f1.y); o0[6]=f2bf(f1.z); o0[7]=f2bf(f1.w);
        o1[0]=f2bf(f2.x); o1[1]=f2bf(f2.y); o1[2]=f2bf(f2.z); o1[3]=f2bf(f2.w);
        o1[4]=f2bf(f3.x); o1[5]=f2bf(f3.y); o1[6]=f2bf(f3.z); o1[7]=f2bf(f3.w);
        *(short8*)&xb[base] = o0;
        *(short8*)&xb[base + 8] = o1;
        return;
    }
    if (blk >= 752) {
        int base = (blk - 752) * 4096 + tid * 16;
        float4 z = make_float4(0.f, 0.f, 0.f, 0.f);
        *(float4*)&Acomb[base] = z;
        *(float4*)&Acomb[base + 4] = z;
        *(float4*)&Acomb[base + 8] = z;
        *(float4*)&Acomb[base + 12] = z;
        return;
    }
    const float* src; int ld, c0, n0, k0, ldd; ushort* dst;
    if (blk < 624) {
        int b3 = blk - 80; int nt = b3 >> 4, kt = b3 & 15;
        n0 = nt * 64; k0 = kt * 64;
        if (n0 < 512)       { src = Wq;  c0 = n0;        ld = 512; }
        else if (n0 < 1024) { src = Wk;  c0 = n0 - 512;  ld = 512; }
        else if (n0 < 1536) { src = Wv;  c0 = n0 - 1024; ld = 512; }
        else if (n0 < 1600) { src = Wb;  c0 = n0 - 1536; ld = 64;  }
        else if (n0 < 1664) { src = Wtg; c0 = n0 - 1600; ld = 64;  }
        else                { src = Wg;  c0 = n0 - 1664; ld = 512; }
        dst = wtb; ldd = 1024;
    } else {
        int b4 = blk - 624; int nt = b4 >> 3, kt = b4 & 7;
        n0 = nt * 64; k0 = kt * 64;
        src = Wo; c0 = n0; ld = 1024; dst = wotb; ldd = 512;
    }
    #pragma unroll
    for (int rep = 0; rep < 4; rep++) {
        int k = rep * 16 + (tid >> 4);
        int nc = (tid & 15) * 4;
        float4 f = *(const float4*)&src[(size_t)(k0 + k) * ld + c0 + nc];
        tile[nc + 0][k] = f2bf(f.x);
        tile[nc + 1][k] = f2bf(f.y);
        tile[nc + 2][k] = f2bf(f.z);
        tile[nc + 3][k] = f2bf(f.w);
    }
    __syncthreads();
    #pragma unroll
    for (int rep = 0; rep < 4; rep++) {
        int n = rep * 16 + (tid >> 4);
        int kc = (tid & 15) * 4;
        uint2 uu = *(const uint2*)&tile[n][kc];
        *(uint2*)&dst[(size_t)(n0 + n) * ldd + k0 + kc] = uu;
    }
}

// ---------------- Kernel 2: proj MFMA GEMM (unchanged) ---------------------------------
__global__ __launch_bounds__(256, 2) void proj_mfma(const ushort* __restrict__ Ab,
        const ushort* __restrict__ BTb, float* __restrict__ proj)
{
    __shared__ ushort sA[2][64][40];
    __shared__ ushort sB[2][64][40];
    const int n0 = blockIdx.x * 64, m0 = blockIdx.y * 64;
    const int tid = threadIdx.x;
    const int lane = tid & 63, w = tid >> 6;
    const int wm = w & 1, wn = w >> 1;
    const int l16 = lane & 15, quad = lane >> 4;
    const int srow = tid >> 2, skq = (tid & 3) * 8;
    const ushort* Ag = Ab + (size_t)(m0 + srow) * 1024 + skq;
    const ushort* Bg = BTb + (size_t)(n0 + srow) * 1024 + skq;
    short8 ra = *(const short8*)Ag;
    short8 rb = *(const short8*)Bg;
    float4v acc00 = {0,0,0,0}, acc01 = {0,0,0,0}, acc10 = {0,0,0,0}, acc11 = {0,0,0,0};
    for (int kt = 0; kt < 32; kt++) {
        const int cb = kt & 1;
        *(short8*)&sA[cb][srow][skq] = ra;
        *(short8*)&sB[cb][srow][skq] = rb;
        __syncthreads();
        if (kt + 1 < 32) {
            ra = *(const short8*)(Ag + (kt + 1) * 32);
            rb = *(const short8*)(Bg + (kt + 1) * 32);
        }
        short8 a0 = *(const short8*)&sA[cb][wm * 32 + l16][quad * 8];
        short8 a1 = *(const short8*)&sA[cb][wm * 32 + 16 + l16][quad * 8];
        short8 b0 = *(const short8*)&sB[cb][wn * 32 + l16][quad * 8];
        short8 b1 = *(const short8*)&sB[cb][wn * 32 + 16 + l16][quad * 8];
        acc00 = __builtin_amdgcn_mfma_f32_16x16x32_bf16(a0, b0, acc00, 0, 0, 0);
        acc01 = __builtin_amdgcn_mfma_f32_16x16x32_bf16(a0, b1, acc01, 0, 0, 0);
        acc10 = __builtin_amdgcn_mfma_f32_16x16x32_bf16(a1, b0, acc10, 0, 0, 0);
        acc11 = __builtin_amdgcn_mfma_f32_16x16x32_bf16(a1, b1, acc11, 0, 0, 0);
    }
    const bool sig = (n0 >= 1536);
    const int colb = n0 + wn * 32 + l16;
    const int rowb = m0 + wm * 32 + quad * 4;
    #pragma unroll
    for (int r2 = 0; r2 < 4; r2++) {
        float v00 = acc00[r2], v01 = acc01[r2], v10 = acc10[r2], v11 = acc11[r2];
        if (sig) {
            v00 = 1.0f / (1.0f + expf(-v00));
            v01 = 1.0f / (1.0f + expf(-v01));
            v10 = 1.0f / (1.0f + expf(-v10));
            v11 = 1.0f / (1.0f + expf(-v11));
        }
        proj[(size_t)(rowb + r2) * NPROJ + colb] = v00;
        proj[(size_t)(rowb + r2) * NPROJ + colb + 16] = v01;
        proj[(size_t)(rowb + 16 + r2) * NPROJ + colb] = v10;
        proj[(size_t)(rowb + 16 + r2) * NPROJ + colb + 16] = v11;
    }
}

// ---------------- Kernel 3: scan — latency-pipelined (A + sc*B linearization) ----------
// pk_t = D2_t*A_t + sc_{t-1}*B'_t ; A_t reduced one step early; B',F',kq,D2 chunk-hoisted.
// grid 512 = b(2) x hr(64) x s(4); block 256: vl = tid>>4, kl = tid&15 (4 k each)
__global__ __launch_bounds__(256, 2) void scan_kernel(const float* __restrict__ proj,
        const float* __restrict__ cosw, const float* __restrict__ sinw,
        const float* __restrict__ rho, const float* __restrict__ modew,
        float* __restrict__ Acomb)
{
    __shared__ uint2 qks[2][CH][16][2];  // packed bf16: [0]=k quad, [1]=q quad   16 KB
    __shared__ float2 vg[2][CH][16];     // {v, gate}                               8 KB
    __shared__ float sc8[2][CH][8];      // 0=beta 1=d 2=kq 3=B' 4=F' 5=D2          2 KB
    __shared__ float obuf[CH][16];       //                                         2 KB
    __shared__ float cwS[64];            // cosw staged for hoist

    const int bi = blockIdx.x;
    const int s  = bi & 3;
    const int hr = (bi >> 2) & 63;
    const int b  = bi >> 8;
    const int h = hr >> 3, r = hr & 7;
    const int tid = threadIdx.x;
    const int vl = tid >> 4;
    const int kl = tid & 15;

    float2v cw0, cw1, sw0, sw1;
    cw0.x = cosw[hr * 64 + kl * 4 + 0]; cw0.y = cosw[hr * 64 + kl * 4 + 1];
    cw1.x = cosw[hr * 64 + kl * 4 + 2]; cw1.y = cosw[hr * 64 + kl * 4 + 3];
    sw0.x = sinw[hr * 64 + kl * 4 + 0]; sw0.y = sinw[hr * 64 + kl * 4 + 1];
    sw1.x = sinw[hr * 64 + kl * 4 + 2]; sw1.y = sinw[hr * 64 + kl * 4 + 3];
    // double-angle rotors
    float2v c2w0 = cw0 * cw0 - sw0 * sw0;
    float2v c2w1 = cw1 * cw1 - sw1 * sw1;
    float2v s2w0 = cw0 * sw0; s2w0 = s2w0 + s2w0;
    float2v s2w1 = cw1 * sw1; s2w1 = s2w1 + s2w1;

    const float rho_hr = rho[hr];
    const float mw = modew[hr];
    // carried state (c = value BEFORE next chunk's step 0)
    float2v crS0 = {0,0}, crS1 = {0,0}, ciS0 = {0,0}, ciS1 = {0,0};

    const float* pb = proj + (size_t)b * T_ * NPROJ;
    const int qbase = h * 64;
    const int kbase = 512 + h * 64;
    const int vbase = 1024 + h * 64 + s * 16;
    const int gbase = 1664 + h * 64 + s * 16;
    const int boff  = 1536 + h * 8 + r;
    const int goff  = 1600 + h * 8 + r;

    if (tid < 64) cwS[tid] = cosw[hr * 64 + tid];

    // stage chunk 0
    {
        #pragma unroll
        for (int rep = 0; rep < 4; rep++) {
            int idx = rep * 256 + tid;
            int t = idx >> 5, sub = idx & 31;
            const float* row = pb + (size_t)t * NPROJ;
            float4 f = *(const float4*)(row + (sub < 16 ? qbase + sub * 4
                                                        : kbase + (sub - 16) * 4));
            uint2 pk2; pk2.x = pack_bf(f.x, f.y); pk2.y = pack_bf(f.z, f.w);
            qks[0][t][sub & 15][sub < 16 ? 1 : 0] = pk2;
        }
        #pragma unroll
        for (int rep = 0; rep < 2; rep++) {
            int idx = rep * 256 + tid;
            int t = idx >> 4, v2 = idx & 15;
            const float* row = pb + (size_t)t * NPROJ;
            vg[0][t][v2] = make_float2(row[vbase + v2], row[gbase + v2]);
        }
        if (tid < CH)            sc8[0][tid][0]      = pb[(size_t)tid * NPROJ + boff];
        else if (tid < 2 * CH)   sc8[0][tid - CH][1] = pb[(size_t)(tid - CH) * NPROJ + goff] * rho_hr;
    }
    __syncthreads();

    float* dstb = Acomb + ((size_t)b * 128) * 512 + h * 64 + s * 16;

    for (int c = 0; c < T_ / CH; c++) {
        const int cb = c & 1, nb = cb ^ 1;
        const bool have = (c + 1 < T_ / CH);

        // --- global prefetch chunk c+1 ---
        float4 g_qk[4]; float2 g_vg[2]; float g_sc = 0.0f;
        if (have) {
            const int t0 = (c + 1) * CH;
            #pragma unroll
            for (int rep = 0; rep < 4; rep++) {
                int idx = rep * 256 + tid;
                int t = idx >> 5, sub = idx & 31;
                const float* row = pb + (size_t)(t0 + t) * NPROJ;
                g_qk[rep] = *(const float4*)(row + (sub < 16 ? qbase + sub * 4
                                                             : kbase + (sub - 16) * 4));
            }
            #pragma unroll
            for (int rep = 0; rep < 2; rep++) {
                int idx = rep * 256 + tid;
                int t = idx >> 4, v2 = idx & 15;
                const float* row = pb + (size_t)(t0 + t) * NPROJ;
                g_vg[rep] = make_float2(row[vbase + v2], row[gbase + v2]);
            }
            if (tid < CH)          g_sc = pb[(size_t)(t0 + tid) * NPROJ + boff];
            else if (tid < 2 * CH) g_sc = pb[(size_t)(t0 + tid - CH) * NPROJ + goff];
        }

        // --- hoist per t: kq, B' = d*sum(cosw k_{t-1} k_t), F' = d*sum(cosw k_{t-1} q_t), D2 ---
        {
            int t = tid >> 3, j = tid & 7;
            int tp = (t > 0) ? t - 1 : 0;
            uint4 wl = *(const uint4*)&qks[cb][t][2 * j][0];
            uint4 wh = *(const uint4*)&qks[cb][t][2 * j + 1][0];
            uint4 pl = *(const uint4*)&qks[cb][tp][2 * j][0];
            uint4 ph = *(const uint4*)&qks[cb][tp][2 * j + 1][0];
            float4 cwa = *(const float4*)&cwS[8 * j];
            float4 cwb = *(const float4*)&cwS[8 * j + 4];
            float2v kt0; kt0.x=bf_lo(wl.x); kt0.y=bf_hi(wl.x);
            float2v kt1; kt1.x=bf_lo(wl.y); kt1.y=bf_hi(wl.y);
            float2v kt2; kt2.x=bf_lo(wh.x); kt2.y=bf_hi(wh.x);
            float2v kt3; kt3.x=bf_lo(wh.y); kt3.y=bf_hi(wh.y);
            float2v qt0; qt0.x=bf_lo(wl.z); qt0.y=bf_hi(wl.z);
            float2v qt1; qt1.x=bf_lo(wl.w); qt1.y=bf_hi(wl.w);
            float2v qt2; qt2.x=bf_lo(wh.z); qt2.y=bf_hi(wh.z);
            float2v qt3; qt3.x=bf_lo(wh.w); qt3.y=bf_hi(wh.w);
            float2v kp0; kp0.x=bf_lo(pl.x); kp0.y=bf_hi(pl.x);
            float2v kp1; kp1.x=bf_lo(pl.y); kp1.y=bf_hi(pl.y);
            float2v kp2; kp2.x=bf_lo(ph.x); kp2.y=bf_hi(ph.x);
            float2v kp3; kp3.x=bf_lo(ph.y); kp3.y=bf_hi(ph.y);
            float2v cva; cva.x=cwa.x; cva.y=cwa.y;
            float2v cvb; cvb.x=cwa.z; cvb.y=cwa.w;
            float2v cvc; cvc.x=cwb.x; cvc.y=cwb.y;
            float2v cvd; cvd.x=cwb.z; cvd.y=cwb.w;
            float2v kqv = kt0*qt0 + kt1*qt1 + kt2*qt2 + kt3*qt3;
            float2v ck0 = cva*kp0, ck1 = cvb*kp1, ck2 = cvc*kp2, ck3 = cvd*kp3;
            float2v Bv = ck0*kt0 + ck1*kt1 + ck2*kt2 + ck3*kt3;
            float2v Fv = ck0*qt0 + ck1*qt1 + ck2*qt2 + ck3*qt3;
            float kq = kqv.x + kqv.y, Bs = Bv.x + Bv.y, Fs = Fv.x + Fv.y;
            kq = dpp_add<0xB1>(kq);  Bs = dpp_add<0xB1>(Bs);  Fs = dpp_add<0xB1>(Fs);
            kq = dpp_add<0x4E>(kq);  Bs = dpp_add<0x4E>(Bs);  Fs = dpp_add<0x4E>(Fs);
            kq = dpp_add<0x141>(kq); Bs = dpp_add<0x141>(Bs); Fs = dpp_add<0x141>(Fs);
            if (j == 0) {
                float dt = sc8[cb][t][1];
                float dp = (t > 0) ? sc8[cb][t - 1][1] : 0.0f;
                sc8[cb][t][2] = kq;
                sc8[cb][t][3] = dt * Bs;
                sc8[cb][t][4] = dt * Fs;
                sc8[cb][t][5] = dt * dp;
            }
        }
        // --- flush previous chunk's outputs ---
        if (c > 0) {
            #pragma unroll
            for (int rep = 0; rep < 2; rep++) {
                int idx = rep * 256 + tid;
                int t = idx >> 4, v2 = idx & 15;
                atomicAdd(dstb + (size_t)((c - 1) * CH + t) * 512 + v2, obuf[t][v2]);
            }
        }
        __syncthreads();

        // ======== step 0 (direct) + pipeline priming ========
        float4 svA = *(const float4*)&sc8[cb][0][0];    // beta,d,kq,B'
        float2 svB = *(const float2*)&sc8[cb][0][4];    // F',D2 (unused at t=0)
        float2 vgv = vg[cb][0][vl];
        uint4 w0 = *(const uint4*)&qks[cb][0][kl][0];
        uint4 wC = *(const uint4*)&qks[cb][1][kl][0];
        float2v k0a; k0a.x=bf_lo(w0.x); k0a.y=bf_hi(w0.x);
        float2v k0b; k0b.x=bf_lo(w0.y); k0b.y=bf_hi(w0.y);
        float2v q0a; q0a.x=bf_lo(w0.z); q0a.y=bf_hi(w0.z);
        float2v q0b; q0b.x=bf_lo(w0.w); q0b.y=bf_hi(w0.w);
        float2v kCa; kCa.x=bf_lo(wC.x); kCa.y=bf_hi(wC.x);
        float2v kCb; kCb.x=bf_lo(wC.y); kCb.y=bf_hi(wC.y);
        float2v qCa; qCa.x=bf_lo(wC.z); qCa.y=bf_hi(wC.z);
        float2v qCb; qCb.x=bf_lo(wC.w); qCb.y=bf_hi(wC.w);
        float d0 = svA.y;
        float2v dv0; dv0.x = d0; dv0.y = d0;
        float2v rrPa = dv0 * (cw0 * crS0 - sw0 * ciS0);
        float2v rrPb = dv0 * (cw1 * crS1 - sw1 * ciS1);
        float2v ciPa = dv0 * (sw0 * crS0 + cw0 * ciS0);
        float2v ciPb = dv0 * (sw1 * crS1 + cw1 * ciS1);
        float2v pkv = rrPa * k0a + rrPb * k0b;
        float2v pqv = rrPa * q0a + rrPb * q0b;
        float pk0 = pkv.x + pkv.y, pq0 = pqv.x + pqv.y;
        // prime A_1/C_1 from c_{-1} = (crS, ciS)
        float2v r2a = c2w0 * crS0 - s2w0 * ciS0;
        float2v r2b = c2w1 * crS1 - s2w1 * ciS1;
        float2v av = r2a * kCa + r2b * kCb;
        float2v cv = r2a * qCa + r2b * qCb;
        float A = av.x + av.y, Cc = cv.x + cv.y;
        pk0 = dpp_add<0xB1>(pk0);  pq0 = dpp_add<0xB1>(pq0);
        A   = dpp_add<0xB1>(A);    Cc  = dpp_add<0xB1>(Cc);
        pk0 = dpp_add<0x4E>(pk0);  pq0 = dpp_add<0x4E>(pq0);
        A   = dpp_add<0x4E>(A);    Cc  = dpp_add<0x4E>(Cc);
        pk0 = dpp_add<0x141>(pk0); pq0 = dpp_add<0x141>(pq0);
        A   = dpp_add<0x141>(A);   Cc  = dpp_add<0x141>(Cc);
        pk0 = dpp_add<0x140>(pk0); pq0 = dpp_add<0x140>(pq0);
        A   = dpp_add<0x140>(A);   Cc  = dpp_add<0x140>(Cc);
        float scp = svA.x * (vgv.x - pk0);
        float rp0 = pq0 + scp * svA.z;
        if (kl == 0) obuf[0][vl] = mw * rp0 * vgv.y;
        float2v kPa = k0a, kPb = k0b;
        // prefetch for t=1
        svA = *(const float4*)&sc8[cb][1][0];
        svB = *(const float2*)&sc8[cb][1][4];
        vgv = vg[cb][1][vl];
        uint4 wA = *(const uint4*)&qks[cb][2][kl][0];   // W_2 for t=1's A/C

        // ======== steps 1..31 (pipelined) ========
        #pragma unroll
        for (int t = 1; t < CH; t++) {
            float4 svA_n; float2 svB_n; float2 vg_n; uint4 wB_;
            if (t + 1 < CH) {
                svA_n = *(const float4*)&sc8[cb][t + 1][0];
                svB_n = *(const float2*)&sc8[cb][t + 1][4];
                vg_n  = vg[cb][t + 1][vl];
            }
            if (t + 2 < CH) wB_ = *(const uint4*)&qks[cb][t + 2][kl][0];

            // critical scalar chain: pk = D2*A + scp*B' -> sc
            float pk = svB.y * A + scp * svA.w;
            float sc = svA.x * (vgv.x - pk);
            float rp = svB.y * Cc + scp * svB.x + sc * svA.z;
            if (kl == 0) obuf[t][vl] = mw * rp * vgv.y;

            // form real part of c_{t-1}
            float2v scp2; scp2.x = scp; scp2.y = scp;
            float2v crPa = rrPa + scp2 * kPa;
            float2v crPb = rrPb + scp2 * kPb;

            // A_{t+1}/C_{t+1} from c_{t-1} (double-angle rotation), reduced off-path
            float2v kNa, kNb;
            float An = 0.0f, Cn = 0.0f;
            if (t + 1 < CH) {
                float2v ra2 = c2w0 * crPa - s2w0 * ciPa;
                float2v rb2 = c2w1 * crPb - s2w1 * ciPb;
                kNa.x = bf_lo(wA.x); kNa.y = bf_hi(wA.x);
                kNb.x = bf_lo(wA.y); kNb.y = bf_hi(wA.y);
                float2v qNa; qNa.x = bf_lo(wA.z); qNa.y = bf_hi(wA.z);
                float2v qNb; qNb.x = bf_lo(wA.w); qNb.y = bf_hi(wA.w);
                float2v av2 = ra2 * kNa + rb2 * kNb;
                float2v cv2 = ra2 * qNa + rb2 * qNb;
                An = av2.x + av2.y; Cn = cv2.x + cv2.y;
                An = dpp_add<0xB1>(An);  Cn = dpp_add<0xB1>(Cn);
                An = dpp_add<0x4E>(An);  Cn = dpp_add<0x4E>(Cn);
                An = dpp_add<0x141>(An); Cn = dpp_add<0x141>(Cn);
                An = dpp_add<0x140>(An); Cn = dpp_add<0x140>(Cn);
            }

            // state rotation for step t (single angle, scaled by d_t)
            float d = svA.y;
            float2v dv; dv.x = d; dv.y = d;
            float2v rrNa = dv * (cw0 * crPa - sw0 * ciPa);
            float2v rrNb = dv * (cw1 * crPb - sw1 * ciPb);
            float2v ciNa = dv * (sw0 * crPa + cw0 * ciPa);
            float2v ciNb = dv * (sw1 * crPb + cw1 * ciPb);
            rrPa = rrNa; rrPb = rrNb; ciPa = ciNa; ciPb = ciNb;
            kPa = kCa; kPb = kCb;
            if (t + 1 < CH) {
                kCa = kNa; kCb = kNb;
                A = An; Cc = Cn;
                svA = svA_n; svB = svB_n; vgv = vg_n; wA = wB_;
            }
            scp = sc;
        }
        // carry state to next chunk: c_31 = (rr_31 + sc_31*k_31, ci_31)
        {
            float2v scp2; scp2.x = scp; scp2.y = scp;
            crS0 = rrPa + scp2 * kPa; crS1 = rrPb + scp2 * kPb;
            ciS0 = ciPa; ciS1 = ciPb;
        }

        // --- write staged registers into the other LDS buffer ---
        if (have) {
            #pragma unroll
            for (int rep = 0; rep < 4; rep++) {
                int idx = rep * 256 + tid;
                int t = idx >> 5, sub = idx & 31;
                float4 f = g_qk[rep];
                uint2 pk2; pk2.x = pack_bf(f.x, f.y); pk2.y = pack_bf(f.z, f.w);
                qks[nb][t][sub & 15][sub < 16 ? 1 : 0] = pk2;
            }
            #pragma unroll
            for (int rep = 0; rep < 2; rep++) {
                int idx = rep * 256 + tid;
                int t = idx >> 4, v2 = idx & 15;
                vg[nb][t][v2] = g_vg[rep];
            }
            if (tid < CH)          sc8[nb][tid][0]      = g_sc;
            else if (tid < 2 * CH) sc8[nb][tid - CH][1] = g_sc * rho_hr;
        }
        __syncthreads();
    }
    // final flush
    #pragma unroll
    for (int rep = 0; rep < 2; rep++) {
        int idx = rep * 256 + tid;
        int t = idx >> 4, v2 = idx & 15;
        atomicAdd(dstb + (size_t)(3 * CH + t) * 512 + v2, obuf[t][v2]);
    }
}

// ---------------- Kernel 4: output GEMM (unchanged) ------------------------------------
__global__ __launch_bounds__(256, 2) void out_mfma(const float* __restrict__ Af,
        const ushort* __restrict__ BTb, float* __restrict__ C)
{
    __shared__ ushort sA[2][64][40];
    __shared__ ushort sB[2][64][40];
    const int n0 = blockIdx.x * 64, m0 = blockIdx.y * 64;
    const int tid = threadIdx.x;
    const int lane = tid & 63, w = tid >> 6;
    const int wm = w & 1, wn = w >> 1;
    const int l16 = lane & 15, quad = lane >> 4;
    const int srow = tid >> 2, skq = (tid & 3) * 8;
    const float* Ag = Af + (size_t)(m0 + srow) * 512 + skq;
    const ushort* Bg = BTb + (size_t)(n0 + srow) * 512 + skq;
    float4 fa0 = *(const float4*)Ag;
    float4 fa1 = *(const float4*)(Ag + 4);
    short8 rb = *(const short8*)Bg;
    float4v acc00 = {0,0,0,0}, acc01 = {0,0,0,0}, acc10 = {0,0,0,0}, acc11 = {0,0,0,0};
    for (int kt = 0; kt < 16; kt++) {
        const int cb = kt & 1;
        short8 ra;
        ra[0]=f2bf(fa0.x); ra[1]=f2bf(fa0.y); ra[2]=f2bf(fa0.z); ra[3]=f2bf(fa0.w);
        ra[4]=f2bf(fa1.x); ra[5]=f2bf(fa1.y); ra[6]=f2bf(fa1.z); ra[7]=f2bf(fa1.w);
        *(short8*)&sA[cb][srow][skq] = ra;
        *(short8*)&sB[cb][srow][skq] = rb;
        __syncthreads();
        if (kt + 1 < 16) {
            fa0 = *(const float4*)(Ag + (kt + 1) * 32);
            fa1 = *(const float4*)(Ag + (kt + 1) * 32 + 4);
            rb = *(const short8*)(Bg + (kt + 1) * 32);
        }
        short8 a0 = *(const short8*)&sA[cb][wm * 32 + l16][quad * 8];
        short8 a1 = *(const short8*)&sA[cb][wm * 32 + 16 + l16][quad * 8];
        short8 b0 = *(const short8*)&sB[cb][wn * 32 + l16][quad * 8];
        short8 b1 = *(const short8*)&sB[cb][wn * 32 + 16 + l16][quad * 8];
        acc00 = __builtin_amdgcn_mfma_f32_16x16x32_bf16(a0, b0, acc00, 0, 0, 0);
        acc01 = __builtin_amdgcn_mfma_f32_16x16x32_bf16(a0, b1, acc01, 0, 0, 0);
        acc10 = __builtin_amdgcn_mfma_f32_16x16x32_bf16(a1, b0, acc10, 0, 0, 0);
        acc11 = __builtin_amdgcn_mfma_f32_16x16x32_bf16(a1, b1, acc11, 0, 0, 0);
    }
    const int colb = n0 + wn * 32 + l16;
    const int rowb = m0 + wm * 32 + quad * 4;
    #pragma unroll
    for (int r2 = 0; r2 < 4; r2++) {
        C[(size_t)(rowb + r2) * 1024 + colb] = acc00[r2];
        C[(size_t)(rowb + r2) * 1024 + colb + 16] = acc01[r2];
        C[(size_t)(rowb + 16 + r2) * 1024 + colb] = acc10[r2];
        C[(size_t)(rowb + 16 + r2) * 1024 + colb + 16] = acc11[r2];
    }
}

extern "C" void kernel_launch(void* const* d_in, const int* in_sizes, int n_in,
                              void* d_out, int out_size, void* d_ws, size_t ws_size,
                              hipStream_t stream) {
    const float* x   = (const float*)d_in[0];
    const float* Wq  = (const float*)d_in[1];
    const float* Wk  = (const float*)d_in[2];
    const float* Wv  = (const float*)d_in[3];
    const float* Wb  = (const float*)d_in[4];
    const float* Wtg = (const float*)d_in[5];
    const float* ml  = (const float*)d_in[6];
    const float* ldc = (const float*)d_in[7];
    const float* ols = (const float*)d_in[8];
    const float* Wg  = (const float*)d_in[9];
    const float* Wo  = (const float*)d_in[10];
    float* out = (float*)d_out;

    float* ws = (float*)d_ws;
    float* proj    = ws;                                 // 557056 f
    float* cosw    = proj + 256 * NPROJ;                 // 4096
    float* sinw    = cosw + 4096;                        // 4096
    float* rho     = sinw + 4096;                        // 64
    float* modew   = rho + 64;                           // 64
    ushort* xb     = (ushort*)(modew + 64);              // 262144 us = 131072 f
    ushort* wotb   = (ushort*)((float*)xb + 131072);     // 524288 us = 262144 f
    float*  Acomb  = (float*)wotb + 262144;              // 131072 f
    ushort* wtb    = (ushort*)(Acomb + 131072);          // 2228224 us = 1114112 f

    prep_kernel<<<784, 256, 0, stream>>>(x, Wq, Wk, Wv, Wb, Wtg, Wg, Wo,
                                         ml, ldc, ols, cosw, sinw, rho, modew,
                                         xb, wtb, wotb, Acomb);
    proj_mfma<<<dim3(34, 4), 256, 0, stream>>>(xb, wtb, proj);
    scan_kernel<<<512, 256, 0, stream>>>(proj, cosw, sinw, rho, modew, Acomb);
    out_mfma<<<dim3(16, 4), 256, 0, stream>>>(Acomb, wotb, out);
}

// Round 12
// 136.952 us; speedup vs baseline: 1.0483x; 1.0483x over previous
//
#include <hip/hip_runtime.h>
#include <math.h>

#define T_ 128
#define NPROJ 2176  // cols: [0,512)=Q [512,1024)=K [1024,1536)=V [1536,1600)=beta [1600,1664)=tg [1664,2176)=gate
#define CH 32       // scan chunk

typedef __attribute__((ext_vector_type(8))) short short8;
typedef __attribute__((ext_vector_type(4))) float float4v;
typedef __attribute__((ext_vector_type(2))) float float2v;

__device__ __forceinline__ ushort f2bf(float x) {
    unsigned u = __float_as_uint(x);
    u += 0x7FFF + ((u >> 16) & 1);   // RNE
    return (ushort)(u >> 16);
}
// pack two fp32 -> one dword of 2 bf16 (round-to-nearest, no tie fix)
__device__ __forceinline__ unsigned pack_bf(float a, float b) {
    unsigned ua = (__float_as_uint(a) + 0x8000u) >> 16;
    unsigned ub = (__float_as_uint(b) + 0x8000u) & 0xffff0000u;
    return ua | ub;
}
__device__ __forceinline__ float bf_lo(unsigned w) { return __uint_as_float(w << 16); }
__device__ __forceinline__ float bf_hi(unsigned w) { return __uint_as_float(w & 0xffff0000u); }

// fused DPP butterfly add: compiles to a single v_add_f32_dpp
template<int CTRL>
__device__ __forceinline__ float dpp_add(float x) {
    int xi = __float_as_int(x);
    int yi = __builtin_amdgcn_update_dpp(xi, xi, CTRL, 0xF, 0xF, false);
    return x + __int_as_float(yi);
}

// ---------------- Kernel 1: prep = params + x->bf16 + W/Wo transpose + Acomb zero -----
__global__ __launch_bounds__(256) void prep_kernel(
    const float* __restrict__ x,
    const float* __restrict__ Wq, const float* __restrict__ Wk,
    const float* __restrict__ Wv, const float* __restrict__ Wb,
    const float* __restrict__ Wtg, const float* __restrict__ Wg,
    const float* __restrict__ Wo,
    const float* __restrict__ mode_logits, const float* __restrict__ log_decay,
    const float* __restrict__ ols,
    float* __restrict__ cosw, float* __restrict__ sinw,
    float* __restrict__ rho, float* __restrict__ modew,
    ushort* __restrict__ xb, ushort* __restrict__ wtb, ushort* __restrict__ wotb,
    float* __restrict__ Acomb)
{
    __shared__ ushort tile[64][68];
    const int blk = blockIdx.x, tid = threadIdx.x;
    if (blk < 16) {
        int idx = blk * 256 + tid;
        if (idx >= 64 * 64) return;
        int t = idx >> 6;   // hr
        int k = idx & 63;
        int h = t >> 3;
        if (k == 0) {
            float ld = log_decay[t];
            rho[t] = 1.0f / (1.0f + expf(ld));  // exp(-softplus) == sigmoid(-x)
            float m = -1e30f;
            for (int i = 0; i < 8; i++) m = fmaxf(m, mode_logits[h * 8 + i]);
            float sum = 0.0f;
            for (int i = 0; i < 8; i++) sum += expf(mode_logits[h * 8 + i] - m);
            modew[t] = expf(mode_logits[t] - m) / sum;
        }
        float osc = expf(ols[t]);
        int p = k >> 1;
        float invf = expf(-((float)(2 * p) / 64.0f) * logf(10000.0f));
        float w = osc * invf;
        cosw[idx] = cosf(w);
        sinw[idx] = sinf(w);
        return;
    }
    if (blk < 80) {   // x convert
        int base = (blk - 16) * 4096 + tid * 16;
        float4 f0 = *(const float4*)&x[base];
        float4 f1 = *(const float4*)&x[base + 4];
        float4 f2 = *(const float4*)&x[base + 8];
        float4 f3 = *(const float4*)&x[base + 12];
        short8 o0, o1;
        o0[0]=f2bf(f0.x); o0[1]=f2bf(f0.y); o0[2]=f2bf(f0.z); o0[3]=f2bf(f0.w);
        o0[4]=f2bf(f1.x); o0[5]=f2bf(f1.y); o0[6]=f2bf(f1.z); o0[7]=f2bf(f1.w);
        o1[0]=f2bf(f2.x); o1[1]=f2bf(f2.y); o1[2]=f2bf(f2.z); o1[3]=f2bf(f2.w);
        o1[4]=f2bf(f3.x); o1[5]=f2bf(f3.y); o1[6]=f2bf(f3.z); o1[7]=f2bf(f3.w);
        *(short8*)&xb[base] = o0;
        *(short8*)&xb[base + 8] = o1;
        return;
    }
    if (blk >= 752) {  // zero Acomb
        int base = (blk - 752) * 4096 + tid * 16;
        float4 z = make_float4(0.f, 0.f, 0.f, 0.f);
        *(float4*)&Acomb[base] = z;
        *(float4*)&Acomb[base + 4] = z;
        *(float4*)&Acomb[base + 8] = z;
        *(float4*)&Acomb[base + 12] = z;
        return;
    }
    // transpose-convert
    const float* src; int ld, c0, n0, k0, ldd; ushort* dst;
    if (blk < 624) {
        int b3 = blk - 80; int nt = b3 >> 4, kt = b3 & 15;
        n0 = nt * 64; k0 = kt * 64;
        if (n0 < 512)       { src = Wq;  c0 = n0;        ld = 512; }
        else if (n0 < 1024) { src = Wk;  c0 = n0 - 512;  ld = 512; }
        else if (n0 < 1536) { src = Wv;  c0 = n0 - 1024; ld = 512; }
        else if (n0 < 1600) { src = Wb;  c0 = n0 - 1536; ld = 64;  }
        else if (n0 < 1664) { src = Wtg; c0 = n0 - 1600; ld = 64;  }
        else                { src = Wg;  c0 = n0 - 1664; ld = 512; }
        dst = wtb; ldd = 1024;
    } else {
        int b4 = blk - 624; int nt = b4 >> 3, kt = b4 & 7;
        n0 = nt * 64; k0 = kt * 64;
        src = Wo; c0 = n0; ld = 1024; dst = wotb; ldd = 512;
    }
    #pragma unroll
    for (int rep = 0; rep < 4; rep++) {
        int k = rep * 16 + (tid >> 4);
        int nc = (tid & 15) * 4;
        float4 f = *(const float4*)&src[(size_t)(k0 + k) * ld + c0 + nc];
        tile[nc + 0][k] = f2bf(f.x);
        tile[nc + 1][k] = f2bf(f.y);
        tile[nc + 2][k] = f2bf(f.z);
        tile[nc + 3][k] = f2bf(f.w);
    }
    __syncthreads();
    #pragma unroll
    for (int rep = 0; rep < 4; rep++) {
        int n = rep * 16 + (tid >> 4);
        int kc = (tid & 15) * 4;
        uint2 uu = *(const uint2*)&tile[n][kc];
        *(uint2*)&dst[(size_t)(n0 + n) * ldd + k0 + kc] = uu;
    }
}

// ---------------- Kernel 2: proj MFMA GEMM ---------------------------------------------
__global__ __launch_bounds__(256, 2) void proj_mfma(const ushort* __restrict__ Ab,
        const ushort* __restrict__ BTb, float* __restrict__ proj)
{
    __shared__ ushort sA[2][64][40];
    __shared__ ushort sB[2][64][40];
    const int n0 = blockIdx.x * 64, m0 = blockIdx.y * 64;
    const int tid = threadIdx.x;
    const int lane = tid & 63, w = tid >> 6;
    const int wm = w & 1, wn = w >> 1;
    const int l16 = lane & 15, quad = lane >> 4;
    const int srow = tid >> 2, skq = (tid & 3) * 8;
    const ushort* Ag = Ab + (size_t)(m0 + srow) * 1024 + skq;
    const ushort* Bg = BTb + (size_t)(n0 + srow) * 1024 + skq;
    short8 ra = *(const short8*)Ag;
    short8 rb = *(const short8*)Bg;
    float4v acc00 = {0,0,0,0}, acc01 = {0,0,0,0}, acc10 = {0,0,0,0}, acc11 = {0,0,0,0};
    for (int kt = 0; kt < 32; kt++) {
        const int cb = kt & 1;
        *(short8*)&sA[cb][srow][skq] = ra;
        *(short8*)&sB[cb][srow][skq] = rb;
        __syncthreads();
        if (kt + 1 < 32) {
            ra = *(const short8*)(Ag + (kt + 1) * 32);
            rb = *(const short8*)(Bg + (kt + 1) * 32);
        }
        short8 a0 = *(const short8*)&sA[cb][wm * 32 + l16][quad * 8];
        short8 a1 = *(const short8*)&sA[cb][wm * 32 + 16 + l16][quad * 8];
        short8 b0 = *(const short8*)&sB[cb][wn * 32 + l16][quad * 8];
        short8 b1 = *(const short8*)&sB[cb][wn * 32 + 16 + l16][quad * 8];
        acc00 = __builtin_amdgcn_mfma_f32_16x16x32_bf16(a0, b0, acc00, 0, 0, 0);
        acc01 = __builtin_amdgcn_mfma_f32_16x16x32_bf16(a0, b1, acc01, 0, 0, 0);
        acc10 = __builtin_amdgcn_mfma_f32_16x16x32_bf16(a1, b0, acc10, 0, 0, 0);
        acc11 = __builtin_amdgcn_mfma_f32_16x16x32_bf16(a1, b1, acc11, 0, 0, 0);
    }
    const bool sig = (n0 >= 1536);
    const int colb = n0 + wn * 32 + l16;
    const int rowb = m0 + wm * 32 + quad * 4;
    #pragma unroll
    for (int r2 = 0; r2 < 4; r2++) {
        float v00 = acc00[r2], v01 = acc01[r2], v10 = acc10[r2], v11 = acc11[r2];
        if (sig) {
            v00 = 1.0f / (1.0f + expf(-v00));
            v01 = 1.0f / (1.0f + expf(-v01));
            v10 = 1.0f / (1.0f + expf(-v10));
            v11 = 1.0f / (1.0f + expf(-v11));
        }
        proj[(size_t)(rowb + r2) * NPROJ + colb] = v00;
        proj[(size_t)(rowb + r2) * NPROJ + colb + 16] = v01;
        proj[(size_t)(rowb + 16 + r2) * NPROJ + colb] = v10;
        proj[(size_t)(rowb + 16 + r2) * NPROJ + colb + 16] = v11;
    }
}

// ---------------- Kernel 3: scan — bf16-packed k|q LDS (1 b128/step), reg dbuf ---------
// grid 512 = b(2) x hr(64) x s(4); block 256: vl = tid>>4 (16 v), kl = tid&15 (4 k each)
__global__ __launch_bounds__(256, 2) void scan_kernel(const float* __restrict__ proj,
        const float* __restrict__ cosw, const float* __restrict__ sinw,
        const float* __restrict__ rho, const float* __restrict__ modew,
        float* __restrict__ Acomb)
{
    __shared__ uint2 qks[2][CH][16][2];  // per (t,kl): [0]={k0..3 bf16}, [1]={q0..3}  16 KB
    __shared__ float2 vg[2][CH][16];     // {v, gate} per (t, vl)                       8 KB
    __shared__ float sc4[2][CH][4];      // [0]=beta [1]=tg [2]=kq                      1 KB
    __shared__ float obuf[CH][16];       // per-chunk outputs                           2 KB

    const int bi = blockIdx.x;
    const int s  = bi & 3;
    const int hr = (bi >> 2) & 63;
    const int b  = bi >> 8;
    const int h = hr >> 3, r = hr & 7;
    const int tid = threadIdx.x;
    const int vl = tid >> 4;             // 0..15
    const int kl = tid & 15;             // 0..15, low 4 lane bits

    float2v cw0, cw1, sw0, sw1;
    cw0.x = cosw[hr * 64 + kl * 4 + 0]; cw0.y = cosw[hr * 64 + kl * 4 + 1];
    cw1.x = cosw[hr * 64 + kl * 4 + 2]; cw1.y = cosw[hr * 64 + kl * 4 + 3];
    sw0.x = sinw[hr * 64 + kl * 4 + 0]; sw0.y = sinw[hr * 64 + kl * 4 + 1];
    sw1.x = sinw[hr * 64 + kl * 4 + 2]; sw1.y = sinw[hr * 64 + kl * 4 + 3];
    const float rho_hr = rho[hr];
    const float mw = modew[hr];
    float2v sr0 = {0,0}, sr1 = {0,0}, si0 = {0,0}, si1 = {0,0};

    const float* pb = proj + (size_t)b * T_ * NPROJ;
    const int qbase = h * 64;
    const int kbase = 512 + h * 64;
    const int vbase = 1024 + h * 64 + s * 16;
    const int gbase = 1664 + h * 64 + s * 16;
    const int boff  = 1536 + h * 8 + r;
    const int goff  = 1600 + h * 8 + r;

    // stage chunk 0 directly global->LDS (fp32 -> packed bf16 for q,k)
    {
        #pragma unroll
        for (int rep = 0; rep < 4; rep++) {
            int idx = rep * 256 + tid;
            int t = idx >> 5, sub = idx & 31;
            const float* row = pb + (size_t)t * NPROJ;
            float4 f = *(const float4*)(row + (sub < 16 ? qbase + sub * 4
                                                        : kbase + (sub - 16) * 4));
            uint2 pk2; pk2.x = pack_bf(f.x, f.y); pk2.y = pack_bf(f.z, f.w);
            qks[0][t][sub & 15][sub < 16 ? 1 : 0] = pk2;
        }
        #pragma unroll
        for (int rep = 0; rep < 2; rep++) {
            int idx = rep * 256 + tid;
            int t = idx >> 4, v2 = idx & 15;
            const float* row = pb + (size_t)t * NPROJ;
            vg[0][t][v2] = make_float2(row[vbase + v2], row[gbase + v2]);
        }
        if (tid < CH)            sc4[0][tid][0]      = pb[(size_t)tid * NPROJ + boff];
        else if (tid < 2 * CH)   sc4[0][tid - CH][1] = pb[(size_t)(tid - CH) * NPROJ + goff];
    }
    __syncthreads();

    float* dstb = Acomb + ((size_t)b * 128) * 512 + h * 64 + s * 16;

    for (int c = 0; c < T_ / CH; c++) {
        const int cb = c & 1, nb = cb ^ 1;
        const bool have = (c + 1 < T_ / CH);

        // --- global prefetch chunk c+1 into registers ---
        float4 g_qk[4]; float2 g_vg[2]; float g_sc = 0.0f;
        if (have) {
            const int t0 = (c + 1) * CH;
            #pragma unroll
            for (int rep = 0; rep < 4; rep++) {
                int idx = rep * 256 + tid;
                int t = idx >> 5, sub = idx & 31;
                const float* row = pb + (size_t)(t0 + t) * NPROJ;
                g_qk[rep] = *(const float4*)(row + (sub < 16 ? qbase + sub * 4
                                                             : kbase + (sub - 16) * 4));
            }
            #pragma unroll
            for (int rep = 0; rep < 2; rep++) {
                int idx = rep * 256 + tid;
                int t = idx >> 4, v2 = idx & 15;
                const float* row = pb + (size_t)(t0 + t) * NPROJ;
                g_vg[rep] = make_float2(row[vbase + v2], row[gbase + v2]);
            }
            if (tid < CH)          g_sc = pb[(size_t)(t0 + tid) * NPROJ + boff];
            else if (tid < 2 * CH) g_sc = pb[(size_t)(t0 + tid - CH) * NPROJ + goff];
        }

        // --- hoisted kq_t for this chunk (reads packed bf16) ---
        {
            int t = tid >> 3, j = tid & 7;
            uint4 wa = *(const uint4*)&qks[cb][t][2 * j][0];
            uint4 wb = *(const uint4*)&qks[cb][t][2 * j + 1][0];
            float p = bf_lo(wa.x) * bf_lo(wa.z) + bf_hi(wa.x) * bf_hi(wa.z)
                    + bf_lo(wa.y) * bf_lo(wa.w) + bf_hi(wa.y) * bf_hi(wa.w)
                    + bf_lo(wb.x) * bf_lo(wb.z) + bf_hi(wb.x) * bf_hi(wb.z)
                    + bf_lo(wb.y) * bf_lo(wb.w) + bf_hi(wb.y) * bf_hi(wb.w);
            p = dpp_add<0xB1>(p);   // xor1
            p = dpp_add<0x4E>(p);   // xor2
            p = dpp_add<0x141>(p);  // half-mirror within 8
            if (j == 0) sc4[cb][t][2] = p;
        }
        // --- flush previous chunk's outputs ---
        if (c > 0) {
            #pragma unroll
            for (int rep = 0; rep < 2; rep++) {
                int idx = rep * 256 + tid;
                int t = idx >> 4, v2 = idx & 15;
                atomicAdd(dstb + (size_t)((c - 1) * CH + t) * 512 + v2, obuf[t][v2]);
            }
        }
        __syncthreads();

        // --- 32 steps, single b128 k|q read per step ---
        const float2* vgb = &vg[cb][0][0];
        const float4* svb = (const float4*)&sc4[cb][0][0];

        uint4 w = *(const uint4*)&qks[cb][0][kl][0];
        float4 sv = svb[0];
        float2 vgv = vgb[vl];
        #pragma unroll
        for (int t = 0; t < CH; t++) {
            uint4 w_n; float4 sv_n; float2 vg_n;
            if (t + 1 < CH) {
                w_n = *(const uint4*)&qks[cb][t + 1][kl][0];
                sv_n = svb[t + 1];
                vg_n = vgb[(t + 1) * 16 + vl];
            }

            // unpack bf16 k|q
            float2v k0; k0.x = bf_lo(w.x); k0.y = bf_hi(w.x);
            float2v k1; k1.x = bf_lo(w.y); k1.y = bf_hi(w.y);
            float2v q0; q0.x = bf_lo(w.z); q0.y = bf_hi(w.z);
            float2v q1; q1.x = bf_lo(w.w); q1.y = bf_hi(w.w);

            const float decay = sv.y * rho_hr;
            float2v t1 = cw0 * sr0 - sw0 * si0;
            float2v u1 = sw0 * sr0 + cw0 * si0;
            float2v t2 = cw1 * sr1 - sw1 * si1;
            float2v u2 = sw1 * sr1 + cw1 * si1;
            float2v d2; d2.x = decay; d2.y = decay;
            float2v rr0 = d2 * t1, rr1 = d2 * t2;
            si0 = d2 * u1; si1 = d2 * u2;

            float2v pk2 = rr0 * k0 + rr1 * k1;
            float2v pq2 = rr0 * q0 + rr1 * q1;
            float pk = pk2.x + pk2.y;
            float pq = pq2.x + pq2.y;
            pk = dpp_add<0xB1>(pk);  pq = dpp_add<0xB1>(pq);   // xor1
            pk = dpp_add<0x4E>(pk);  pq = dpp_add<0x4E>(pq);   // xor2
            pk = dpp_add<0x141>(pk); pq = dpp_add<0x141>(pq);  // xor4
            pk = dpp_add<0x140>(pk); pq = dpp_add<0x140>(pq);  // xor8 (mirror in 16)

            const float sc = sv.x * (vgv.x - pk);
            float2v sc2; sc2.x = sc; sc2.y = sc;
            sr0 = rr0 + sc2 * k0;
            sr1 = rr1 + sc2 * k1;
            const float rp = pq + sc * sv.z;    // = sum(sr_new * q)
            if (kl == 0) obuf[t][vl] = mw * rp * vgv.y;

            w = w_n; sv = sv_n; vgv = vg_n;
        }

        // --- write staged registers into the other LDS buffer (convert to bf16) ---
        if (have) {
            #pragma unroll
            for (int rep = 0; rep < 4; rep++) {
                int idx = rep * 256 + tid;
                int t = idx >> 5, sub = idx & 31;
                float4 f = g_qk[rep];
                uint2 pk2; pk2.x = pack_bf(f.x, f.y); pk2.y = pack_bf(f.z, f.w);
                qks[nb][t][sub & 15][sub < 16 ? 1 : 0] = pk2;
            }
            #pragma unroll
            for (int rep = 0; rep < 2; rep++) {
                int idx = rep * 256 + tid;
                int t = idx >> 4, v2 = idx & 15;
                vg[nb][t][v2] = g_vg[rep];
            }
            if (tid < CH)          sc4[nb][tid][0]      = g_sc;
            else if (tid < 2 * CH) sc4[nb][tid - CH][1] = g_sc;
        }
        __syncthreads();
    }
    // final flush
    #pragma unroll
    for (int rep = 0; rep < 2; rep++) {
        int idx = rep * 256 + tid;
        int t = idx >> 4, v2 = idx & 15;
        atomicAdd(dstb + (size_t)(3 * CH + t) * 512 + v2, obuf[t][v2]);
    }
}

// ---------------- Kernel 4: output GEMM, A = fp32 Acomb converted inline ---------------
__global__ __launch_bounds__(256, 2) void out_mfma(const float* __restrict__ Af,
        const ushort* __restrict__ BTb, float* __restrict__ C)
{
    __shared__ ushort sA[2][64][40];
    __shared__ ushort sB[2][64][40];
    const int n0 = blockIdx.x * 64, m0 = blockIdx.y * 64;
    const int tid = threadIdx.x;
    const int lane = tid & 63, w = tid >> 6;
    const int wm = w & 1, wn = w >> 1;
    const int l16 = lane & 15, quad = lane >> 4;
    const int srow = tid >> 2, skq = (tid & 3) * 8;
    const float* Ag = Af + (size_t)(m0 + srow) * 512 + skq;
    const ushort* Bg = BTb + (size_t)(n0 + srow) * 512 + skq;
    float4 fa0 = *(const float4*)Ag;
    float4 fa1 = *(const float4*)(Ag + 4);
    short8 rb = *(const short8*)Bg;
    float4v acc00 = {0,0,0,0}, acc01 = {0,0,0,0}, acc10 = {0,0,0,0}, acc11 = {0,0,0,0};
    for (int kt = 0; kt < 16; kt++) {
        const int cb = kt & 1;
        short8 ra;
        ra[0]=f2bf(fa0.x); ra[1]=f2bf(fa0.y); ra[2]=f2bf(fa0.z); ra[3]=f2bf(fa0.w);
        ra[4]=f2bf(fa1.x); ra[5]=f2bf(fa1.y); ra[6]=f2bf(fa1.z); ra[7]=f2bf(fa1.w);
        *(short8*)&sA[cb][srow][skq] = ra;
        *(short8*)&sB[cb][srow][skq] = rb;
        __syncthreads();
        if (kt + 1 < 16) {
            fa0 = *(const float4*)(Ag + (kt + 1) * 32);
            fa1 = *(const float4*)(Ag + (kt + 1) * 32 + 4);
            rb = *(const short8*)(Bg + (kt + 1) * 32);
        }
        short8 a0 = *(const short8*)&sA[cb][wm * 32 + l16][quad * 8];
        short8 a1 = *(const short8*)&sA[cb][wm * 32 + 16 + l16][quad * 8];
        short8 b0 = *(const short8*)&sB[cb][wn * 32 + l16][quad * 8];
        short8 b1 = *(const short8*)&sB[cb][wn * 32 + 16 + l16][quad * 8];
        acc00 = __builtin_amdgcn_mfma_f32_16x16x32_bf16(a0, b0, acc00, 0, 0, 0);
        acc01 = __builtin_amdgcn_mfma_f32_16x16x32_bf16(a0, b1, acc01, 0, 0, 0);
        acc10 = __builtin_amdgcn_mfma_f32_16x16x32_bf16(a1, b0, acc10, 0, 0, 0);
        acc11 = __builtin_amdgcn_mfma_f32_16x16x32_bf16(a1, b1, acc11, 0, 0, 0);
    }
    const int colb = n0 + wn * 32 + l16;
    const int rowb = m0 + wm * 32 + quad * 4;
    #pragma unroll
    for (int r2 = 0; r2 < 4; r2++) {
        C[(size_t)(rowb + r2) * 1024 + colb] = acc00[r2];
        C[(size_t)(rowb + r2) * 1024 + colb + 16] = acc01[r2];
        C[(size_t)(rowb + 16 + r2) * 1024 + colb] = acc10[r2];
        C[(size_t)(rowb + 16 + r2) * 1024 + colb + 16] = acc11[r2];
    }
}

extern "C" void kernel_launch(void* const* d_in, const int* in_sizes, int n_in,
                              void* d_out, int out_size, void* d_ws, size_t ws_size,
                              hipStream_t stream) {
    const float* x   = (const float*)d_in[0];
    const float* Wq  = (const float*)d_in[1];
    const float* Wk  = (const float*)d_in[2];
    const float* Wv  = (const float*)d_in[3];
    const float* Wb  = (const float*)d_in[4];
    const float* Wtg = (const float*)d_in[5];
    const float* ml  = (const float*)d_in[6];
    const float* ldc = (const float*)d_in[7];
    const float* ols = (const float*)d_in[8];
    const float* Wg  = (const float*)d_in[9];
    const float* Wo  = (const float*)d_in[10];
    float* out = (float*)d_out;

    float* ws = (float*)d_ws;
    float* proj    = ws;                                 // 557056 f
    float* cosw    = proj + 256 * NPROJ;                 // 4096
    float* sinw    = cosw + 4096;                        // 4096
    float* rho     = sinw + 4096;                        // 64
    float* modew   = rho + 64;                           // 64
    ushort* xb     = (ushort*)(modew + 64);              // 262144 us = 131072 f
    ushort* wotb   = (ushort*)((float*)xb + 131072);     // 524288 us = 262144 f
    float*  Acomb  = (float*)wotb + 262144;              // 131072 f
    ushort* wtb    = (ushort*)(Acomb + 131072);          // 2228224 us = 1114112 f

    prep_kernel<<<784, 256, 0, stream>>>(x, Wq, Wk, Wv, Wb, Wtg, Wg, Wo,
                                         ml, ldc, ols, cosw, sinw, rho, modew,
                                         xb, wtb, wotb, Acomb);
    proj_mfma<<<dim3(34, 4), 256, 0, stream>>>(xb, wtb, proj);
    scan_kernel<<<512, 256, 0, stream>>>(proj, cosw, sinw, rho, modew, Acomb);
    out_mfma<<<dim3(16, 4), 256, 0, stream>>>(Acomb, wotb, out);
}